// Round 8
// baseline (784.449 us; speedup 1.0000x reference)
//
#include <hip/hip_runtime.h>
#include <hip/hip_bf16.h>
#include <math.h>

// Problem: B=16, N=512, D=256, H=8, L=4, DFF=1024, K=128, DH=32
#define BB 16
#define NN 512
#define DD 256
#define HH 8
#define LL 4
#define DFF 1024
#define KSEL 128
#define DH 32

typedef __attribute__((ext_vector_type(8))) short bf16x8v;
typedef __attribute__((ext_vector_type(4))) float f32x4v;

// ---------------- workspace layout (byte offsets) ----------------
static const size_t X_B    = 0;
static const size_t QKVB_B = 8388608;
static const size_t VT_B   = 20971520;
static const size_t FFN_B  = 8388608;    // overlays qkvb+Vt (dead during FFN)
static const size_t H_B    = 25165824;
static const size_t ATT_B  = 29360128;
static const size_t WQKV_B = 33554432;
static const size_t WO_B   = 35127296;
static const size_t W1T_B  = 35651584;
static const size_t W2T_B  = 37748736;
static const size_t S_B    = 39845888;
static const size_t MAXD_B = 39878656;   // S_B + 32768
static const size_t IDX_B  = 39878720;   // MAXD_B + 64

// ---------------- helpers ----------------
__device__ __forceinline__ float gelu_f(float x) {
  float x3 = x * x * x;
  return 0.5f * x * (1.f + tanhf(0.7978845608028654f * (x + 0.044715f * x3)));
}

__device__ __forceinline__ short bf16raw(float v) {
  __hip_bfloat16 h = __float2bfloat16(v);
  return *reinterpret_cast<short*>(&h);
}

// async global->LDS direct copy, 16B per lane; lds dest must be wave-uniform
__device__ __forceinline__ void async_copy16(const void* g, void* l) {
  __builtin_amdgcn_global_load_lds(
      (__attribute__((address_space(1))) void*)const_cast<void*>(g),
      (__attribute__((address_space(3))) void*)l, 16, 0, 0);
}

__device__ __forceinline__ float blk_sum_256(float v, float* stmp) {
  #pragma unroll
  for (int o = 32; o > 0; o >>= 1) v += __shfl_down(v, o, 64);
  if ((threadIdx.x & 63) == 0) stmp[threadIdx.x >> 6] = v;
  __syncthreads();
  if (threadIdx.x == 0) stmp[0] = stmp[0] + stmp[1] + stmp[2] + stmp[3];
  __syncthreads();
  float r = stmp[0];
  __syncthreads();
  return r;
}

// ---------------- kernels ----------------
__global__ void copy_kernel(const float4* __restrict__ src, float4* __restrict__ dst, int n) {
  int i = blockIdx.x * blockDim.x + threadIdx.x;
  if (i < n) dst[i] = src[i];
}

// one-shot: transpose-cast all weights to bf16.
__global__ __launch_bounds__(256) void cast_weights_kernel(
    const float* __restrict__ Wq, const float* __restrict__ Wk,
    const float* __restrict__ Wv, const float* __restrict__ Wo,
    const float* __restrict__ W1, const float* __restrict__ W2,
    __hip_bfloat16* __restrict__ qkvT, __hip_bfloat16* __restrict__ WoT,
    __hip_bfloat16* __restrict__ W1T, __hip_bfloat16* __restrict__ W2T) {
  int i = blockIdx.x * 256 + threadIdx.x;
  if (i < 786432) {                       // qkvT [L][768 n][256 k]
    int l = i / 196608, r = i % 196608;
    int n = r >> 8, k = r & 255;
    const float* src = (n < 256) ? Wq : (n < 512 ? Wk : Wv);
    qkvT[i] = __float2bfloat16(src[l * 65536 + k * 256 + (n & 255)]);
  } else if (i < 1048576) {               // WoT [L][256][256]
    int j = i - 786432;
    int l = j >> 16, r = j & 65535;
    int n = r >> 8, k = r & 255;
    WoT[j] = __float2bfloat16(Wo[l * 65536 + k * 256 + n]);
  } else if (i < 2097152) {               // W1T [L][1024 n][256 k]
    int j = i - 1048576;
    int l = j >> 18, r = j & 262143;
    int n = r >> 8, k = r & 255;
    W1T[j] = __float2bfloat16(W1[l * 262144 + k * 1024 + n]);
  } else {                                // W2T [L][256 n][1024 k]
    int j = i - 2097152;
    int l = j >> 18, r = j & 262143;
    int n = r >> 10, k = r & 1023;
    W2T[j] = __float2bfloat16(W2[l * 262144 + k * 256 + n]);
  }
}

// LayerNorm, writes bf16
__global__ __launch_bounds__(256) void ln_cast_kernel(const float* __restrict__ in,
                                                      const float* __restrict__ g,
                                                      const float* __restrict__ bb,
                                                      __hip_bfloat16* __restrict__ out) {
  __shared__ float stmp[4];
  size_t row = blockIdx.x;
  int d = threadIdx.x;
  float v = in[row * DD + d];
  float mu = blk_sum_256(v, stmp) * (1.0f / DD);
  float diff = v - mu;
  float var = blk_sum_256(diff * diff, stmp) * (1.0f / DD);
  out[row * DD + d] = __float2bfloat16(diff * rsqrtf(var + 1e-6f) * g[d] + bb[d]);
}

// MFMA bf16 GEMM, m97-style: 128x128 tile, BK=32, 4 waves, 16 MFMA/K-step,
// global_load_lds width-16 staging with XOR seg swizzle (2-way banks on read).
// acc = A[M,K] @ Bt[N,K]^T
// MODE 1: fp32 out = acc + Res; MODE 2: bf16 out = gelu(acc);
// MODE 3: qkv: cols<512 -> bf16 qkvb (pitch 768); cols>=512 -> Vt[b][dim][key].
template <int MODE>
__global__ __launch_bounds__(256) void mfma_gemm128(const __hip_bfloat16* __restrict__ A,
                                                    const __hip_bfloat16* __restrict__ Bt,
                                                    const float* __restrict__ Res,
                                                    void* __restrict__ Cv,
                                                    __hip_bfloat16* __restrict__ Vto,
                                                    int M, int N, int Kd) {
  __shared__ short As[128 * 32];
  __shared__ short Bs[128 * 32];
  const int tid = threadIdx.x;
  const int w = tid >> 6, lane = tid & 63;
  const int m16 = lane & 15, quad = lane >> 4;
  const int bm = blockIdx.y << 7, bn = blockIdx.x << 7;
  const int wm = (w & 1) << 6, wn = (w >> 1) << 6;

  f32x4v acc[4][4];
  #pragma unroll
  for (int i = 0; i < 4; ++i)
    #pragma unroll
    for (int j = 0; j < 4; ++j) acc[i][j] = (f32x4v){0.f, 0.f, 0.f, 0.f};

  const short* Ag = (const short*)A + (size_t)bm * Kd;
  const short* Bg = (const short*)Bt + (size_t)bn * Kd;
  const int lrow = lane >> 2;                               // 0..15
  const int gseg = (((lane & 3) ^ ((lane >> 3) & 3)) << 3); // swizzled store seg
  const int pseg = ((quad ^ ((m16 >> 1) & 3)) << 3);        // swizzled read seg

  for (int k0 = 0; k0 < Kd; k0 += 32) {
    #pragma unroll
    for (int i = 0; i < 2; ++i) {
      const int r0 = w * 32 + i * 16;   // wave-uniform
      async_copy16(Ag + (size_t)(r0 + lrow) * Kd + k0 + gseg, &As[r0 * 32]);
      async_copy16(Bg + (size_t)(r0 + lrow) * Kd + k0 + gseg, &Bs[r0 * 32]);
    }
    __syncthreads();   // drains vmcnt (incl. global_load_lds) + barrier
    bf16x8v af[4], bf[4];
    #pragma unroll
    for (int i = 0; i < 4; ++i) {
      af[i] = *(const bf16x8v*)&As[(wm + i * 16 + m16) * 32 + pseg];
      bf[i] = *(const bf16x8v*)&Bs[(wn + i * 16 + m16) * 32 + pseg];
    }
    #pragma unroll
    for (int i = 0; i < 4; ++i)
      #pragma unroll
      for (int j = 0; j < 4; ++j)
        acc[i][j] = __builtin_amdgcn_mfma_f32_16x16x32_bf16(af[i], bf[j], acc[i][j], 0, 0, 0);
    __syncthreads();
  }

  #pragma unroll
  for (int i = 0; i < 4; ++i) {
    const int erow = bm + wm + i * 16 + quad * 4;
    #pragma unroll
    for (int j = 0; j < 4; ++j) {
      const int col = bn + wn + j * 16 + m16;
      if (MODE == 3) {
        if (col < 512) {
          #pragma unroll
          for (int r = 0; r < 4; ++r)
            ((__hip_bfloat16*)Cv)[(size_t)(erow + r) * 768 + col] =
                __float2bfloat16(acc[i][j][r]);
        } else {
          short4 pk;
          pk.x = bf16raw(acc[i][j][0]); pk.y = bf16raw(acc[i][j][1]);
          pk.z = bf16raw(acc[i][j][2]); pk.w = bf16raw(acc[i][j][3]);
          int bb2 = erow >> 9, key = erow & 511, dim = col - 512;
          *(short4*)((short*)Vto + (size_t)bb2 * 131072 + (size_t)dim * 512 + key) = pk;
        }
      } else {
        #pragma unroll
        for (int r = 0; r < 4; ++r) {
          float v = acc[i][j][r];
          size_t off = (size_t)(erow + r) * N + col;
          if (MODE == 1) ((float*)Cv)[off] = v + Res[off];
          else ((__hip_bfloat16*)Cv)[off] = __float2bfloat16(gelu_f(v));
        }
      }
    }
  }
}

// MFMA flash attention, barrier-free (unchanged).
__global__ __launch_bounds__(512) void attn_kernel(const __hip_bfloat16* __restrict__ qkvb,
                                                   const __hip_bfloat16* __restrict__ vt,
                                                   const float* __restrict__ dist,
                                                   __hip_bfloat16* __restrict__ outg,
                                                   float* __restrict__ s_acc,
                                                   int accum) {
  __shared__ float Pf[8][16 * 36];
  const int tid = threadIdx.x;
  const int h = tid >> 6, lane = tid & 63;
  const int m16 = lane & 15, quad = lane >> 4;
  const int b = blockIdx.y;
  const int qbase = blockIdx.x * 16;
  const float scale = 0.17677669529663687f;
  const f32x4v zero = {0.f, 0.f, 0.f, 0.f};

  const short* qkvs = (const short*)qkvb;
  const short* vts = (const short*)vt + (size_t)b * 131072;
  float* Pw = Pf[h];

  bf16x8v qf = *(const bf16x8v*)(qkvs + ((size_t)(b * NN + qbase + m16)) * 768 + h * 32 + (quad << 3));

  int drow[4];
  #pragma unroll
  for (int r = 0; r < 4; ++r) drow[r] = (b * NN + qbase + quad * 4 + r) * NN;

  f32x4v accO0 = zero, accO1 = zero;
  float lacc[4] = {0.f, 0.f, 0.f, 0.f};

  for (int t0 = 0; t0 < NN; t0 += 32) {
    bf16x8v kf0 = *(const bf16x8v*)(qkvs + ((size_t)(b * NN + t0 + m16)) * 768 + 256 + h * 32 + (quad << 3));
    bf16x8v kf1 = *(const bf16x8v*)(qkvs + ((size_t)(b * NN + t0 + 16 + m16)) * 768 + 256 + h * 32 + (quad << 3));
    f32x4v s0 = __builtin_amdgcn_mfma_f32_16x16x32_bf16(qf, kf0, zero, 0, 0, 0);
    f32x4v s1 = __builtin_amdgcn_mfma_f32_16x16x32_bf16(qf, kf1, zero, 0, 0, 0);
    #pragma unroll
    for (int r = 0; r < 4; ++r) {
      float e0 = __expf(fmaf(s0[r], scale, -dist[drow[r] + t0 + m16]));
      float e1 = __expf(fmaf(s1[r], scale, -dist[drow[r] + t0 + 16 + m16]));
      float t = e0 + e1;
      t += __shfl_xor(t, 1, 64); t += __shfl_xor(t, 2, 64);
      t += __shfl_xor(t, 4, 64); t += __shfl_xor(t, 8, 64);
      lacc[r] += t;
      Pw[(quad * 4 + r) * 36 + m16] = e0;
      Pw[(quad * 4 + r) * 36 + 16 + m16] = e1;
    }
    bf16x8v pfr;
    {
      const float* pr = &Pw[m16 * 36 + (quad << 3)];
      float4 pa = *(const float4*)pr;
      float4 pb = *(const float4*)(pr + 4);
      pfr[0] = bf16raw(pa.x); pfr[1] = bf16raw(pa.y);
      pfr[2] = bf16raw(pa.z); pfr[3] = bf16raw(pa.w);
      pfr[4] = bf16raw(pb.x); pfr[5] = bf16raw(pb.y);
      pfr[6] = bf16raw(pb.z); pfr[7] = bf16raw(pb.w);
    }
    bf16x8v vf0 = *(const bf16x8v*)(vts + (size_t)(h * 32 + m16) * 512 + t0 + (quad << 3));
    bf16x8v vf1 = *(const bf16x8v*)(vts + (size_t)(h * 32 + 16 + m16) * 512 + t0 + (quad << 3));
    accO0 = __builtin_amdgcn_mfma_f32_16x16x32_bf16(pfr, vf0, accO0, 0, 0, 0);
    accO1 = __builtin_amdgcn_mfma_f32_16x16x32_bf16(pfr, vf1, accO1, 0, 0, 0);
  }

  float invl[4];
  #pragma unroll
  for (int r = 0; r < 4; ++r) invl[r] = 1.f / lacc[r];

  #pragma unroll
  for (int r = 0; r < 4; ++r) {
    size_t orow = (size_t)(b * NN + qbase + quad * 4 + r) * DD + h * 32;
    outg[orow + m16] = __float2bfloat16(accO0[r] * invl[r]);
    outg[orow + 16 + m16] = __float2bfloat16(accO1[r] * invl[r]);
  }

  if (accum) {
    for (int t0 = 0; t0 < NN; t0 += 32) {
      bf16x8v kf0 = *(const bf16x8v*)(qkvs + ((size_t)(b * NN + t0 + m16)) * 768 + 256 + h * 32 + (quad << 3));
      bf16x8v kf1 = *(const bf16x8v*)(qkvs + ((size_t)(b * NN + t0 + 16 + m16)) * 768 + 256 + h * 32 + (quad << 3));
      f32x4v s0 = __builtin_amdgcn_mfma_f32_16x16x32_bf16(qf, kf0, zero, 0, 0, 0);
      f32x4v s1 = __builtin_amdgcn_mfma_f32_16x16x32_bf16(qf, kf1, zero, 0, 0, 0);
      float p0 = 0.f, p1 = 0.f;
      #pragma unroll
      for (int r = 0; r < 4; ++r) {
        p0 += __expf(fmaf(s0[r], scale, -dist[drow[r] + t0 + m16])) * invl[r];
        p1 += __expf(fmaf(s1[r], scale, -dist[drow[r] + t0 + 16 + m16])) * invl[r];
      }
      p0 += __shfl_xor(p0, 16, 64); p0 += __shfl_xor(p0, 32, 64);
      p1 += __shfl_xor(p1, 16, 64); p1 += __shfl_xor(p1, 32, 64);
      if (quad == 0) {
        atomicAdd(&s_acc[b * NN + t0 + m16], p0 * 0.125f);
        atomicAdd(&s_acc[b * NN + t0 + 16 + m16], p1 * 0.125f);
      }
    }
  }
}

// parallel max over dist[b] via float-as-uint atomicMax (values >= 0).
__global__ __launch_bounds__(256) void maxd_kernel(const float* __restrict__ dist,
                                                   unsigned int* __restrict__ maxd) {
  const int b = blockIdx.y;
  const int tid = threadIdx.x;
  const float4* p = (const float4*)(dist + (size_t)b * NN * NN) +
                    blockIdx.x * 8192 + tid;
  float m = 0.f;
  #pragma unroll 8
  for (int i = 0; i < 32; ++i) {
    float4 v = p[i * 256];
    m = fmaxf(m, fmaxf(fmaxf(v.x, v.y), fmaxf(v.z, v.w)));
  }
  #pragma unroll
  for (int o = 32; o > 0; o >>= 1) m = fmaxf(m, __shfl_xor(m, o, 64));
  __shared__ float wm[4];
  if ((tid & 63) == 0) wm[tid >> 6] = m;
  __syncthreads();
  if (tid == 0) {
    float mm = fmaxf(fmaxf(wm[0], wm[1]), fmaxf(wm[2], wm[3]));
    atomicMax(&maxd[b], __float_as_uint(mm));
  }
}

// AFPS selection: one wave per batch, barrier-free, registers only.
__global__ __launch_bounds__(64) void afps_select_kernel(const float* __restrict__ dist,
                                                         const float* __restrict__ s,
                                                         const unsigned int* __restrict__ maxd,
                                                         int* __restrict__ idx_out) {
  const int b = blockIdx.x;
  const int lane = threadIdx.x;
  const float* db = dist + (size_t)b * NN * NN;

  float sv[8];
  float ms = 0.f;
  #pragma unroll
  for (int r = 0; r < 8; ++r) {
    sv[r] = s[b * NN + r * 64 + lane];
    ms = fmaxf(ms, sv[r]);
  }
  #pragma unroll
  for (int o = 32; o > 0; o >>= 1) ms = fmaxf(ms, __shfl_xor(ms, o, 64));

  const float invmaxd = 1.0f / __uint_as_float(maxd[b]);
  float sn[8], mind[8];
  #pragma unroll
  for (int r = 0; r < 8; ++r) {
    sn[r] = (sv[r] / ms) * 0.1f;
    mind[r] = db[r * 64 + lane] * invmaxd + sn[r];   // row 0 == col 0 (sym)
  }
  unsigned selm = (lane == 0) ? 1u : 0u;
  if (lane == 0) idx_out[b * KSEL + 0] = 0;

  for (int it = 1; it < KSEL; ++it) {
    float bestv = -INFINITY;
    int besti = 0x7fffffff;
    #pragma unroll
    for (int r = 0; r < 8; ++r) {
      float v = (selm >> r) & 1u ? -INFINITY : mind[r];
      int idx = r * 64 + lane;
      if (v > bestv || (v == bestv && idx < besti)) { bestv = v; besti = idx; }
    }
    #pragma unroll
    for (int o = 32; o > 0; o >>= 1) {
      float ov = __shfl_xor(bestv, o, 64);
      int oi = __shfl_xor(besti, o, 64);
      if (ov > bestv || (ov == bestv && oi < besti)) { bestv = ov; besti = oi; }
    }
    const int nw = besti;
    if (lane == (nw & 63)) selm |= 1u << (nw >> 6);
    if (lane == 0) idx_out[b * KSEL + it] = nw;
    const float* row = db + (size_t)nw * NN;
    #pragma unroll
    for (int r = 0; r < 8; ++r)
      mind[r] = fminf(mind[r], row[r * 64 + lane] * invmaxd + sn[r]);
  }
}

// one block per batch: gather K rows, mean, LN -> out
__global__ __launch_bounds__(256) void pool_ln_kernel(const float* __restrict__ x,
                                                      const int* __restrict__ idx,
                                                      const float* __restrict__ gamma,
                                                      const float* __restrict__ beta,
                                                      float* __restrict__ out) {
  __shared__ float stmp[4];
  __shared__ int sIdx[KSEL];
  const int b = blockIdx.x;
  const int d = threadIdx.x;
  if (d < KSEL) sIdx[d] = idx[b * KSEL + d];
  __syncthreads();
  float acc = 0.f;
  #pragma unroll 4
  for (int kk = 0; kk < KSEL; ++kk)
    acc += x[((size_t)b * NN + sIdx[kk]) * DD + d];
  float p = acc * (1.0f / KSEL);
  float mu = blk_sum_256(p, stmp) * (1.0f / DD);
  float diff = p - mu;
  float var = blk_sum_256(diff * diff, stmp) * (1.0f / DD);
  out[b * DD + d] = diff * rsqrtf(var + 1e-6f) * gamma[d] + beta[d];
}

// ---------------- launcher ----------------
extern "C" void kernel_launch(void* const* d_in, const int* in_sizes, int n_in,
                              void* d_out, int out_size, void* d_ws, size_t ws_size,
                              hipStream_t stream) {
  (void)in_sizes; (void)n_in; (void)out_size; (void)ws_size;
  const float* x_in  = (const float*)d_in[0];
  const float* dist  = (const float*)d_in[1];
  const float* Wq    = (const float*)d_in[3];
  const float* Wk    = (const float*)d_in[4];
  const float* Wv    = (const float*)d_in[5];
  const float* Wo    = (const float*)d_in[6];
  const float* W1    = (const float*)d_in[7];
  const float* W2    = (const float*)d_in[8];
  const float* ln1_g = (const float*)d_in[9];
  const float* ln1_b = (const float*)d_in[10];
  const float* ln2_g = (const float*)d_in[11];
  const float* ln2_b = (const float*)d_in[12];
  const float* gamma = (const float*)d_in[13];
  const float* beta  = (const float*)d_in[14];

  char* wsb = (char*)d_ws;
  float* x              = (float*)(wsb + X_B);
  __hip_bfloat16* qkvb  = (__hip_bfloat16*)(wsb + QKVB_B);
  __hip_bfloat16* vtb   = (__hip_bfloat16*)(wsb + VT_B);
  __hip_bfloat16* ffn   = (__hip_bfloat16*)(wsb + FFN_B);
  __hip_bfloat16* hb    = (__hip_bfloat16*)(wsb + H_B);
  __hip_bfloat16* ab    = (__hip_bfloat16*)(wsb + ATT_B);
  __hip_bfloat16* WqkvT = (__hip_bfloat16*)(wsb + WQKV_B);
  __hip_bfloat16* WoT   = (__hip_bfloat16*)(wsb + WO_B);
  __hip_bfloat16* W1T   = (__hip_bfloat16*)(wsb + W1T_B);
  __hip_bfloat16* W2T   = (__hip_bfloat16*)(wsb + W2T_B);
  float* sbuf = (float*)(wsb + S_B);
  unsigned int* maxdb = (unsigned int*)(wsb + MAXD_B);
  int*   idxb = (int*)(wsb + IDX_B);
  float* out  = (float*)d_out;

  copy_kernel<<<2048, 256, 0, stream>>>((const float4*)x_in, (float4*)x, 524288);
  hipMemsetAsync(sbuf, 0, BB * NN * sizeof(float) + 64, stream);  // sbuf + maxd
  cast_weights_kernel<<<12288, 256, 0, stream>>>(Wq, Wk, Wv, Wo, W1, W2,
                                                 WqkvT, WoT, W1T, W2T);
  maxd_kernel<<<dim3(8, BB), 256, 0, stream>>>(dist, maxdb);

  const int M = BB * NN;  // 8192
  dim3 gqkv(768 / 128, M / 128);   // (6,64)
  dim3 go(DD / 128, M / 128);      // (2,64)
  dim3 gf(DFF / 128, M / 128);     // (8,64)
  dim3 ga(NN / 16, BB);            // (32,16)

  for (int l = 0; l < LL; ++l) {
    ln_cast_kernel<<<M, 256, 0, stream>>>(x, ln1_g + l * DD, ln1_b + l * DD, hb);
    mfma_gemm128<3><<<gqkv, 256, 0, stream>>>(hb, WqkvT + (size_t)l * 768 * 256, nullptr,
                                              qkvb, vtb, M, 768, 256);
    attn_kernel<<<ga, 512, 0, stream>>>(qkvb, vtb, dist, ab, sbuf, (l == LL - 1) ? 1 : 0);
    if (l == LL - 1) {
      // dist + s are L2/L3-warm right after the last attention pass
      afps_select_kernel<<<BB, 64, 0, stream>>>(dist, sbuf, maxdb, idxb);
    }
    mfma_gemm128<1><<<go, 256, 0, stream>>>(ab, WoT + (size_t)l * 65536, x, x, nullptr, M, DD, 256);
    ln_cast_kernel<<<M, 256, 0, stream>>>(x, ln2_g + l * DD, ln2_b + l * DD, hb);
    mfma_gemm128<2><<<gf, 256, 0, stream>>>(hb, W1T + (size_t)l * 262144, nullptr,
                                            ffn, nullptr, M, DFF, 256);
    mfma_gemm128<1><<<go, 256, 0, stream>>>(ffn, W2T + (size_t)l * 262144, x, x, nullptr, M, DD, 1024);
  }
  pool_ln_kernel<<<BB, 256, 0, stream>>>(x, idxb, gamma, beta, out);
}

// Round 9
// 700.549 us; speedup vs baseline: 1.1198x; 1.1198x over previous
//
#include <hip/hip_runtime.h>
#include <hip/hip_bf16.h>
#include <math.h>

// Problem: B=16, N=512, D=256, H=8, L=4, DFF=1024, K=128, DH=32
#define BB 16
#define NN 512
#define DD 256
#define HH 8
#define LL 4
#define DFF 1024
#define KSEL 128
#define DH 32

typedef __attribute__((ext_vector_type(8))) short bf16x8v;
typedef __attribute__((ext_vector_type(4))) float f32x4v;

// ---------------- workspace layout (byte offsets) ----------------
static const size_t X_B    = 0;
static const size_t QKVB_B = 8388608;
static const size_t VT_B   = 20971520;
static const size_t FFN_B  = 8388608;    // overlays qkvb+Vt (dead during FFN)
static const size_t H_B    = 25165824;
static const size_t ATT_B  = 29360128;
static const size_t WQKV_B = 33554432;
static const size_t WO_B   = 35127296;
static const size_t W1T_B  = 35651584;
static const size_t W2T_B  = 37748736;
static const size_t S_B    = 39845888;
static const size_t MAXD_B = 39878656;   // S_B + 32768
static const size_t IDX_B  = 39878720;   // MAXD_B + 64

// ---------------- helpers ----------------
__device__ __forceinline__ float gelu_f(float x) {
  float x3 = x * x * x;
  return 0.5f * x * (1.f + tanhf(0.7978845608028654f * (x + 0.044715f * x3)));
}

__device__ __forceinline__ short bf16raw(float v) {
  __hip_bfloat16 h = __float2bfloat16(v);
  return *reinterpret_cast<short*>(&h);
}

__device__ __forceinline__ float blk_sum_256(float v, float* stmp) {
  #pragma unroll
  for (int o = 32; o > 0; o >>= 1) v += __shfl_down(v, o, 64);
  if ((threadIdx.x & 63) == 0) stmp[threadIdx.x >> 6] = v;
  __syncthreads();
  if (threadIdx.x == 0) stmp[0] = stmp[0] + stmp[1] + stmp[2] + stmp[3];
  __syncthreads();
  float r = stmp[0];
  __syncthreads();
  return r;
}

// ---------------- kernels ----------------
__global__ void copy_kernel(const float4* __restrict__ src, float4* __restrict__ dst, int n) {
  int i = blockIdx.x * blockDim.x + threadIdx.x;
  if (i < n) dst[i] = src[i];
}

// one-shot: transpose-cast all weights to bf16.
__global__ __launch_bounds__(256) void cast_weights_kernel(
    const float* __restrict__ Wq, const float* __restrict__ Wk,
    const float* __restrict__ Wv, const float* __restrict__ Wo,
    const float* __restrict__ W1, const float* __restrict__ W2,
    __hip_bfloat16* __restrict__ qkvT, __hip_bfloat16* __restrict__ WoT,
    __hip_bfloat16* __restrict__ W1T, __hip_bfloat16* __restrict__ W2T) {
  int i = blockIdx.x * 256 + threadIdx.x;
  if (i < 786432) {                       // qkvT [L][768 n][256 k]
    int l = i / 196608, r = i % 196608;
    int n = r >> 8, k = r & 255;
    const float* src = (n < 256) ? Wq : (n < 512 ? Wk : Wv);
    qkvT[i] = __float2bfloat16(src[l * 65536 + k * 256 + (n & 255)]);
  } else if (i < 1048576) {               // WoT [L][256][256]
    int j = i - 786432;
    int l = j >> 16, r = j & 65535;
    int n = r >> 8, k = r & 255;
    WoT[j] = __float2bfloat16(Wo[l * 65536 + k * 256 + n]);
  } else if (i < 2097152) {               // W1T [L][1024 n][256 k]
    int j = i - 1048576;
    int l = j >> 18, r = j & 262143;
    int n = r >> 8, k = r & 255;
    W1T[j] = __float2bfloat16(W1[l * 262144 + k * 1024 + n]);
  } else {                                // W2T [L][256 n][1024 k]
    int j = i - 2097152;
    int l = j >> 18, r = j & 262143;
    int n = r >> 10, k = r & 1023;
    W2T[j] = __float2bfloat16(W2[l * 262144 + k * 256 + n]);
  }
}

// LayerNorm, writes bf16
__global__ __launch_bounds__(256) void ln_cast_kernel(const float* __restrict__ in,
                                                      const float* __restrict__ g,
                                                      const float* __restrict__ bb,
                                                      __hip_bfloat16* __restrict__ out) {
  __shared__ float stmp[4];
  size_t row = blockIdx.x;
  int d = threadIdx.x;
  float v = in[row * DD + d];
  float mu = blk_sum_256(v, stmp) * (1.0f / DD);
  float diff = v - mu;
  float var = blk_sum_256(diff * diff, stmp) * (1.0f / DD);
  out[row * DD + d] = __float2bfloat16(diff * rsqrtf(var + 1e-6f) * g[d] + bb[d]);
}

// MFMA bf16 GEMM (64x64 tile, BK=32, 4 waves) — R7 configuration.
// acc = A[M,K] @ Bt[N,K]^T
// MODE 1: fp32 out = acc + Res; MODE 2: bf16 out = gelu(acc);
// MODE 3: qkv: cols<512 -> bf16 qkvb (pitch 768); cols>=512 -> Vt[b][dim][key].
template <int MODE>
__global__ __launch_bounds__(256) void mfma_gemm(const __hip_bfloat16* __restrict__ A,
                                                 const __hip_bfloat16* __restrict__ Bt,
                                                 const float* __restrict__ Res,
                                                 void* __restrict__ Cv,
                                                 __hip_bfloat16* __restrict__ Vto,
                                                 int M, int N, int Kd) {
  __shared__ short As[64 * 40];
  __shared__ short Bs[64 * 40];
  const int tid = threadIdx.x;
  const int w = tid >> 6, lane = tid & 63;
  const int m16 = lane & 15, quad = lane >> 4;
  const int bm = blockIdx.y << 6, bn = blockIdx.x << 6;
  const int srow = tid >> 2, scol = (tid & 3) << 3;

  f32x4v zero = {0.f, 0.f, 0.f, 0.f};
  f32x4v acc[4];
  #pragma unroll
  for (int nt = 0; nt < 4; ++nt) acc[nt] = zero;

  const short* Ag = (const short*)A;
  const short* Bg = (const short*)Bt;

  for (int k0 = 0; k0 < Kd; k0 += 32) {
    *(bf16x8v*)&As[srow * 40 + scol] =
        *(const bf16x8v*)(Ag + (size_t)(bm + srow) * Kd + k0 + scol);
    *(bf16x8v*)&Bs[srow * 40 + scol] =
        *(const bf16x8v*)(Bg + (size_t)(bn + srow) * Kd + k0 + scol);
    __syncthreads();
    bf16x8v af = *(bf16x8v*)&As[(w * 16 + m16) * 40 + (quad << 3)];
    #pragma unroll
    for (int nt = 0; nt < 4; ++nt) {
      bf16x8v bf = *(bf16x8v*)&Bs[(nt * 16 + m16) * 40 + (quad << 3)];
      acc[nt] = __builtin_amdgcn_mfma_f32_16x16x32_bf16(af, bf, acc[nt], 0, 0, 0);
    }
    __syncthreads();
  }

  const int erow = bm + w * 16 + quad * 4;
  #pragma unroll
  for (int nt = 0; nt < 4; ++nt) {
    int col = bn + nt * 16 + m16;
    if (MODE == 3) {
      if (col < 512) {
        #pragma unroll
        for (int r = 0; r < 4; ++r)
          ((__hip_bfloat16*)Cv)[(size_t)(erow + r) * 768 + col] =
              __float2bfloat16(acc[nt][r]);
      } else {
        short4 pk;
        pk.x = bf16raw(acc[nt][0]); pk.y = bf16raw(acc[nt][1]);
        pk.z = bf16raw(acc[nt][2]); pk.w = bf16raw(acc[nt][3]);
        int bb2 = erow >> 9, key = erow & 511, dim = col - 512;
        *(short4*)((short*)Vto + (size_t)bb2 * 131072 + (size_t)dim * 512 + key) = pk;
      }
    } else {
      #pragma unroll
      for (int r = 0; r < 4; ++r) {
        float v = acc[nt][r];
        size_t off = (size_t)(erow + r) * N + col;
        if (MODE == 1) ((float*)Cv)[off] = v + Res[off];
        else ((__hip_bfloat16*)Cv)[off] = __float2bfloat16(gelu_f(v));
      }
    }
  }
}

// MFMA flash attention, barrier-free; softmax denominator accumulated
// lane-locally and reduced ONCE after the K-loop (removes per-tile shfl chain).
__global__ __launch_bounds__(512) void attn_kernel(const __hip_bfloat16* __restrict__ qkvb,
                                                   const __hip_bfloat16* __restrict__ vt,
                                                   const float* __restrict__ dist,
                                                   __hip_bfloat16* __restrict__ outg,
                                                   float* __restrict__ s_acc,
                                                   int accum) {
  __shared__ float Pf[8][16 * 36];
  const int tid = threadIdx.x;
  const int h = tid >> 6, lane = tid & 63;
  const int m16 = lane & 15, quad = lane >> 4;
  const int b = blockIdx.y;
  const int qbase = blockIdx.x * 16;
  const float scale = 0.17677669529663687f;
  const f32x4v zero = {0.f, 0.f, 0.f, 0.f};

  const short* qkvs = (const short*)qkvb;
  const short* vts = (const short*)vt + (size_t)b * 131072;
  float* Pw = Pf[h];

  bf16x8v qf = *(const bf16x8v*)(qkvs + ((size_t)(b * NN + qbase + m16)) * 768 + h * 32 + (quad << 3));

  int drow[4];
  #pragma unroll
  for (int r = 0; r < 4; ++r) drow[r] = (b * NN + qbase + quad * 4 + r) * NN;

  f32x4v accO0 = zero, accO1 = zero;
  float laccL[4] = {0.f, 0.f, 0.f, 0.f};   // lane-local partial sums

  for (int t0 = 0; t0 < NN; t0 += 32) {
    bf16x8v kf0 = *(const bf16x8v*)(qkvs + ((size_t)(b * NN + t0 + m16)) * 768 + 256 + h * 32 + (quad << 3));
    bf16x8v kf1 = *(const bf16x8v*)(qkvs + ((size_t)(b * NN + t0 + 16 + m16)) * 768 + 256 + h * 32 + (quad << 3));
    f32x4v s0 = __builtin_amdgcn_mfma_f32_16x16x32_bf16(qf, kf0, zero, 0, 0, 0);
    f32x4v s1 = __builtin_amdgcn_mfma_f32_16x16x32_bf16(qf, kf1, zero, 0, 0, 0);
    #pragma unroll
    for (int r = 0; r < 4; ++r) {
      float e0 = __expf(fmaf(s0[r], scale, -dist[drow[r] + t0 + m16]));
      float e1 = __expf(fmaf(s1[r], scale, -dist[drow[r] + t0 + 16 + m16]));
      laccL[r] += e0 + e1;
      Pw[(quad * 4 + r) * 36 + m16] = e0;
      Pw[(quad * 4 + r) * 36 + 16 + m16] = e1;
    }
    bf16x8v pfr;
    {
      const float* pr = &Pw[m16 * 36 + (quad << 3)];
      float4 pa = *(const float4*)pr;
      float4 pb = *(const float4*)(pr + 4);
      pfr[0] = bf16raw(pa.x); pfr[1] = bf16raw(pa.y);
      pfr[2] = bf16raw(pa.z); pfr[3] = bf16raw(pa.w);
      pfr[4] = bf16raw(pb.x); pfr[5] = bf16raw(pb.y);
      pfr[6] = bf16raw(pb.z); pfr[7] = bf16raw(pb.w);
    }
    bf16x8v vf0 = *(const bf16x8v*)(vts + (size_t)(h * 32 + m16) * 512 + t0 + (quad << 3));
    bf16x8v vf1 = *(const bf16x8v*)(vts + (size_t)(h * 32 + 16 + m16) * 512 + t0 + (quad << 3));
    accO0 = __builtin_amdgcn_mfma_f32_16x16x32_bf16(pfr, vf0, accO0, 0, 0, 0);
    accO1 = __builtin_amdgcn_mfma_f32_16x16x32_bf16(pfr, vf1, accO1, 0, 0, 0);
  }

  // one-time row-sum reduction over the 16 m16-lanes (lane bits 0..3)
  float invl[4];
  #pragma unroll
  for (int r = 0; r < 4; ++r) {
    float t = laccL[r];
    t += __shfl_xor(t, 1, 64); t += __shfl_xor(t, 2, 64);
    t += __shfl_xor(t, 4, 64); t += __shfl_xor(t, 8, 64);
    invl[r] = 1.f / t;
  }

  #pragma unroll
  for (int r = 0; r < 4; ++r) {
    size_t orow = (size_t)(b * NN + qbase + quad * 4 + r) * DD + h * 32;
    outg[orow + m16] = __float2bfloat16(accO0[r] * invl[r]);
    outg[orow + 16 + m16] = __float2bfloat16(accO1[r] * invl[r]);
  }

  if (accum) {
    for (int t0 = 0; t0 < NN; t0 += 32) {
      bf16x8v kf0 = *(const bf16x8v*)(qkvs + ((size_t)(b * NN + t0 + m16)) * 768 + 256 + h * 32 + (quad << 3));
      bf16x8v kf1 = *(const bf16x8v*)(qkvs + ((size_t)(b * NN + t0 + 16 + m16)) * 768 + 256 + h * 32 + (quad << 3));
      f32x4v s0 = __builtin_amdgcn_mfma_f32_16x16x32_bf16(qf, kf0, zero, 0, 0, 0);
      f32x4v s1 = __builtin_amdgcn_mfma_f32_16x16x32_bf16(qf, kf1, zero, 0, 0, 0);
      float p0 = 0.f, p1 = 0.f;
      #pragma unroll
      for (int r = 0; r < 4; ++r) {
        p0 += __expf(fmaf(s0[r], scale, -dist[drow[r] + t0 + m16])) * invl[r];
        p1 += __expf(fmaf(s1[r], scale, -dist[drow[r] + t0 + 16 + m16])) * invl[r];
      }
      p0 += __shfl_xor(p0, 16, 64); p0 += __shfl_xor(p0, 32, 64);
      p1 += __shfl_xor(p1, 16, 64); p1 += __shfl_xor(p1, 32, 64);
      if (quad == 0) {
        atomicAdd(&s_acc[b * NN + t0 + m16], p0 * 0.125f);
        atomicAdd(&s_acc[b * NN + t0 + 16 + m16], p1 * 0.125f);
      }
    }
  }
}

// parallel max over dist[b] via float-as-uint atomicMax (values >= 0).
__global__ __launch_bounds__(256) void maxd_kernel(const float* __restrict__ dist,
                                                   unsigned int* __restrict__ maxd) {
  const int b = blockIdx.y;
  const int tid = threadIdx.x;
  const float4* p = (const float4*)(dist + (size_t)b * NN * NN) +
                    blockIdx.x * 8192 + tid;
  float m = 0.f;
  #pragma unroll 8
  for (int i = 0; i < 32; ++i) {
    float4 v = p[i * 256];
    m = fmaxf(m, fmaxf(fmaxf(v.x, v.y), fmaxf(v.z, v.w)));
  }
  #pragma unroll
  for (int o = 32; o > 0; o >>= 1) m = fmaxf(m, __shfl_xor(m, o, 64));
  __shared__ float wm[4];
  if ((tid & 63) == 0) wm[tid >> 6] = m;
  __syncthreads();
  if (tid == 0) {
    float mm = fmaxf(fmaxf(wm[0], wm[1]), fmaxf(wm[2], wm[3]));
    atomicMax(&maxd[b], __float_as_uint(mm));
  }
}

// AFPS selection: one wave per batch, registers only, packed-u64 argmax with
// top-2 tracking + speculative prefetch of the predicted next row.
// Key = (bits(v) << 32) | (511 - idx): monotone for v>=0, ties -> smaller idx
// (matches jnp.argmax first-max). Selected nodes -> key 0.
__global__ __launch_bounds__(64) void afps_select_kernel(const float* __restrict__ dist,
                                                         const float* __restrict__ s,
                                                         const unsigned int* __restrict__ maxd,
                                                         int* __restrict__ idx_out) {
  const int b = blockIdx.x;
  const int lane = threadIdx.x;
  const float* db = dist + (size_t)b * NN * NN;

  float sv[8];
  float ms = 0.f;
  #pragma unroll
  for (int r = 0; r < 8; ++r) {
    sv[r] = s[b * NN + r * 64 + lane];
    ms = fmaxf(ms, sv[r]);
  }
  #pragma unroll
  for (int o = 32; o > 0; o >>= 1) ms = fmaxf(ms, __shfl_xor(ms, o, 64));

  const float invmaxd = 1.0f / __uint_as_float(maxd[b]);
  float sn[8], mind[8];
  #pragma unroll
  for (int r = 0; r < 8; ++r) {
    sn[r] = (sv[r] / ms) * 0.1f;
    mind[r] = db[r * 64 + lane] * invmaxd + sn[r];   // row 0 == col 0 (sym)
  }
  unsigned selm = (lane == 0) ? 1u : 0u;
  if (lane == 0) idx_out[b * KSEL + 0] = 0;

  int specIdx = -1;
  float sreg[8];

  for (int it = 1; it < KSEL; ++it) {
    // local top-2 over this lane's 8 nodes
    unsigned long long b1 = 0ull, b2 = 0ull;
    #pragma unroll
    for (int r = 0; r < 8; ++r) {
      unsigned long long pk =
          ((selm >> r) & 1u) ? 0ull
            : (((unsigned long long)__float_as_uint(mind[r])) << 32) |
              (unsigned)(511 - (r * 64 + lane));
      if (pk > b1) { b2 = b1; b1 = pk; }
      else if (pk > b2) b2 = pk;
    }
    // wave top-2 butterfly
    #pragma unroll
    for (int o = 32; o > 0; o >>= 1) {
      unsigned long long o1 = __shfl_xor(b1, o, 64);
      unsigned long long o2 = __shfl_xor(b2, o, 64);
      unsigned long long n1 = b1 > o1 ? b1 : o1;
      unsigned long long lo = b1 > o1 ? o1 : b1;
      unsigned long long n2 = b2 > o2 ? b2 : o2;
      b2 = lo > n2 ? lo : n2;
      b1 = n1;
    }
    const int nw = 511 - (int)(unsigned)(b1 & 0xffffffffu);
    const int sec = 511 - (int)(unsigned)(b2 & 0xffffffffu);

    float rowv[8];
    if (nw == specIdx) {
      #pragma unroll
      for (int r = 0; r < 8; ++r) rowv[r] = sreg[r];
    } else {
      const float* row = db + (size_t)nw * NN;
      #pragma unroll
      for (int r = 0; r < 8; ++r) rowv[r] = row[r * 64 + lane];
    }
    // speculative prefetch of predicted next pick's row
    {
      const float* srow = db + (size_t)sec * NN;
      #pragma unroll
      for (int r = 0; r < 8; ++r) sreg[r] = srow[r * 64 + lane];
      specIdx = sec;
    }
    if (lane == (nw & 63)) selm |= 1u << (nw >> 6);
    if (lane == 0) idx_out[b * KSEL + it] = nw;
    #pragma unroll
    for (int r = 0; r < 8; ++r)
      mind[r] = fminf(mind[r], fmaf(rowv[r], invmaxd, sn[r]));
  }
}

// one block per batch: gather K rows, mean, LN -> out
__global__ __launch_bounds__(256) void pool_ln_kernel(const float* __restrict__ x,
                                                      const int* __restrict__ idx,
                                                      const float* __restrict__ gamma,
                                                      const float* __restrict__ beta,
                                                      float* __restrict__ out) {
  __shared__ float stmp[4];
  __shared__ int sIdx[KSEL];
  const int b = blockIdx.x;
  const int d = threadIdx.x;
  if (d < KSEL) sIdx[d] = idx[b * KSEL + d];
  __syncthreads();
  float acc = 0.f;
  #pragma unroll 4
  for (int kk = 0; kk < KSEL; ++kk)
    acc += x[((size_t)b * NN + sIdx[kk]) * DD + d];
  float p = acc * (1.0f / KSEL);
  float mu = blk_sum_256(p, stmp) * (1.0f / DD);
  float diff = p - mu;
  float var = blk_sum_256(diff * diff, stmp) * (1.0f / DD);
  out[b * DD + d] = diff * rsqrtf(var + 1e-6f) * gamma[d] + beta[d];
}

// ---------------- launcher ----------------
extern "C" void kernel_launch(void* const* d_in, const int* in_sizes, int n_in,
                              void* d_out, int out_size, void* d_ws, size_t ws_size,
                              hipStream_t stream) {
  (void)in_sizes; (void)n_in; (void)out_size; (void)ws_size;
  const float* x_in  = (const float*)d_in[0];
  const float* dist  = (const float*)d_in[1];
  const float* Wq    = (const float*)d_in[3];
  const float* Wk    = (const float*)d_in[4];
  const float* Wv    = (const float*)d_in[5];
  const float* Wo    = (const float*)d_in[6];
  const float* W1    = (const float*)d_in[7];
  const float* W2    = (const float*)d_in[8];
  const float* ln1_g = (const float*)d_in[9];
  const float* ln1_b = (const float*)d_in[10];
  const float* ln2_g = (const float*)d_in[11];
  const float* ln2_b = (const float*)d_in[12];
  const float* gamma = (const float*)d_in[13];
  const float* beta  = (const float*)d_in[14];

  char* wsb = (char*)d_ws;
  float* x              = (float*)(wsb + X_B);
  __hip_bfloat16* qkvb  = (__hip_bfloat16*)(wsb + QKVB_B);
  __hip_bfloat16* vtb   = (__hip_bfloat16*)(wsb + VT_B);
  __hip_bfloat16* ffn   = (__hip_bfloat16*)(wsb + FFN_B);
  __hip_bfloat16* hb    = (__hip_bfloat16*)(wsb + H_B);
  __hip_bfloat16* ab    = (__hip_bfloat16*)(wsb + ATT_B);
  __hip_bfloat16* WqkvT = (__hip_bfloat16*)(wsb + WQKV_B);
  __hip_bfloat16* WoT   = (__hip_bfloat16*)(wsb + WO_B);
  __hip_bfloat16* W1T   = (__hip_bfloat16*)(wsb + W1T_B);
  __hip_bfloat16* W2T   = (__hip_bfloat16*)(wsb + W2T_B);
  float* sbuf = (float*)(wsb + S_B);
  unsigned int* maxdb = (unsigned int*)(wsb + MAXD_B);
  int*   idxb = (int*)(wsb + IDX_B);
  float* out  = (float*)d_out;

  copy_kernel<<<2048, 256, 0, stream>>>((const float4*)x_in, (float4*)x, 524288);
  hipMemsetAsync(sbuf, 0, BB * NN * sizeof(float) + 64, stream);  // sbuf + maxd
  cast_weights_kernel<<<12288, 256, 0, stream>>>(Wq, Wk, Wv, Wo, W1, W2,
                                                 WqkvT, WoT, W1T, W2T);
  maxd_kernel<<<dim3(8, BB), 256, 0, stream>>>(dist, maxdb);

  const int M = BB * NN;  // 8192
  dim3 gqkv(768 / 64, M / 64);   // (12,128)
  dim3 go(DD / 64, M / 64);      // (4,128)
  dim3 gf(DFF / 64, M / 64);     // (16,128)
  dim3 ga(NN / 16, BB);          // (32,16)

  for (int l = 0; l < LL; ++l) {
    ln_cast_kernel<<<M, 256, 0, stream>>>(x, ln1_g + l * DD, ln1_b + l * DD, hb);
    mfma_gemm<3><<<gqkv, 256, 0, stream>>>(hb, WqkvT + (size_t)l * 768 * 256, nullptr,
                                           qkvb, vtb, M, 768, 256);
    attn_kernel<<<ga, 512, 0, stream>>>(qkvb, vtb, dist, ab, sbuf, (l == LL - 1) ? 1 : 0);
    if (l == LL - 1) {
      afps_select_kernel<<<BB, 64, 0, stream>>>(dist, sbuf, maxdb, idxb);
    }
    mfma_gemm<1><<<go, 256, 0, stream>>>(ab, WoT + (size_t)l * 65536, x, x, nullptr, M, DD, 256);
    ln_cast_kernel<<<M, 256, 0, stream>>>(x, ln2_g + l * DD, ln2_b + l * DD, hb);
    mfma_gemm<2><<<gf, 256, 0, stream>>>(hb, W1T + (size_t)l * 262144, nullptr,
                                         ffn, nullptr, M, DFF, 256);
    mfma_gemm<1><<<go, 256, 0, stream>>>(ffn, W2T + (size_t)l * 262144, x, x, nullptr, M, DD, 1024);
  }
  pool_ln_kernel<<<BB, 256, 0, stream>>>(x, idxb, gamma, beta, out);
}